// Round 6
// baseline (475.816 us; speedup 1.0000x reference)
//
#include <hip/hip_runtime.h>
#include <hip/hip_bf16.h>

#define T_TOK 2048
#define DIM   1024
#define NEXP  16
#define HID   2048
#define J1 256   // per-XCD tile-list capacity, fc1
#define J2 128   // per-XCD tile-list capacity, fc2

typedef __attribute__((ext_vector_type(8))) short short8;
typedef __attribute__((ext_vector_type(4))) float f32x4;

__device__ __forceinline__ unsigned short f2bf(float f) {
  __hip_bfloat16 h = __float2bfloat16(f);
  union { __hip_bfloat16 b; unsigned short u; } cv; cv.b = h; return cv.u;
}

// ---------------- init: zero counters, clear tile lists ----------------
__global__ void init_k(int* cnt, int* fill, int* list1, int* list2) {
  int i = blockIdx.x * 256 + threadIdx.x;
  if (i < NEXP) { cnt[i] = 0; fill[i] = 0; }
  if (i < 8 * J1) list1[i] = -1;
  if (i < 8 * J2) list2[i] = -1;
}

// ---------------- router: fp32, one wave per token ----------------
__global__ __launch_bounds__(256) void router_k(const float* __restrict__ x,
    const float* __restrict__ Wr, const float* __restrict__ br,
    int* __restrict__ re, float* __restrict__ rwv, int* __restrict__ cnt)
{
  const int wid = threadIdx.x >> 6, lane = threadIdx.x & 63;
  const int t = blockIdx.x * 4 + wid;
  const float* xr = x + (size_t)t * DIM;
  float acc[NEXP];
#pragma unroll
  for (int e = 0; e < NEXP; e++) acc[e] = 0.f;
  for (int i = 0; i < DIM / 64; i++) {
    const int d = lane + 64 * i;
    const float xv = xr[d];
    const float4* w4 = reinterpret_cast<const float4*>(Wr + (size_t)d * NEXP);
#pragma unroll
    for (int q = 0; q < 4; q++) {
      float4 w = w4[q];
      acc[4*q+0] += xv * w.x; acc[4*q+1] += xv * w.y;
      acc[4*q+2] += xv * w.z; acc[4*q+3] += xv * w.w;
    }
  }
#pragma unroll
  for (int e = 0; e < NEXP; e++) {
    float v = acc[e];
    v += __shfl_xor(v, 32); v += __shfl_xor(v, 16); v += __shfl_xor(v, 8);
    v += __shfl_xor(v, 4);  v += __shfl_xor(v, 2);  v += __shfl_xor(v, 1);
    acc[e] = v;
  }
  if (lane == 0) {
    float lg[NEXP];
#pragma unroll
    for (int e = 0; e < NEXP; e++) lg[e] = acc[e] + br[e];  // TEMP = 1.0
    int e0 = 0; float b0 = lg[0];
    for (int e = 1; e < NEXP; e++) if (lg[e] > b0) { b0 = lg[e]; e0 = e; }
    int e1 = (e0 == 0) ? 1 : 0; float b1v = lg[e1];
    for (int e = 0; e < NEXP; e++) if (e != e0 && lg[e] > b1v) { b1v = lg[e]; e1 = e; }
    float p1 = expf(b1v - b0);               // p0 = 1
    float inv = 1.0f / (1.0f + p1);
    re[2*t] = e0; re[2*t+1] = e1;
    rwv[2*t] = inv; rwv[2*t+1] = p1 * inv;
    atomicAdd(&cnt[e0], 1); atomicAdd(&cnt[e1], 1);
  }
}

// ---------------- scan: prefix + per-XCD tile lists (expert->XCD affinity) ----
// Tile code: (e<<16) | (mt<<8) | nt.  List x holds tiles whose blocks get
// blockIdx ≡ x (mod 8)  ->  same XCD (round-robin dispatch), so each expert's
// A-panel (512KB..1MB) and W n-panels stay L2-resident on one XCD.
__global__ void scan_k(const int* cnt, int* basev, int* list1, int* list2) {
  if (threadIdx.x != 0) return;
  int s = 0;
  for (int e = 0; e < NEXP; e++) { basev[e] = s; s += cnt[e]; }
  int n1[8] = {0,0,0,0,0,0,0,0}, n2[8] = {0,0,0,0,0,0,0,0};
  for (int e = 0; e < NEXP; e++) {
    const int x = e & 7;
    const int mts = (cnt[e] + 127) >> 7;
    for (int nt = 0; nt < HID / 64; nt++)
      for (int mt = 0; mt < mts; mt++) {        // m-tiles of same (e,nt) adjacent
        int xx = x;
        while (n1[xx] >= J1) xx = (xx + 1) & 7; // overflow fallback (capacity 2048 >= max 1520)
        list1[xx * J1 + n1[xx]++] = (e << 16) | (mt << 8) | nt;
      }
    for (int nt = 0; nt < DIM / 64; nt++)
      for (int mt = 0; mt < mts; mt++) {
        int xx = x;
        while (n2[xx] >= J2) xx = (xx + 1) & 7;
        list2[xx * J2 + n2[xx]++] = (e << 16) | (mt << 8) | nt;
      }
  }
}

// ---------------- scatter: build per-expert row lists ----------------
__global__ __launch_bounds__(256) void scatter_k(const int* __restrict__ re,
    const float* __restrict__ rwv, const int* __restrict__ basev, int* fill,
    int* __restrict__ rows_token, float* __restrict__ rows_w, int* __restrict__ slot_of)
{
  int t = blockIdx.x * 256 + threadIdx.x;
  if (t >= T_TOK) return;
  for (int k = 0; k < 2; k++) {
    int e = re[2*t+k];
    int pos = atomicAdd(&fill[e], 1);
    int row = basev[e] + pos;
    rows_token[row] = t;
    rows_w[row] = rwv[2*t+k];
    slot_of[2*t+k] = row;
  }
}

// ---------------- gather: xg[row] = bf16(x[token]) ----------------
__global__ __launch_bounds__(256) void gather_k(const float* __restrict__ x,
    const int* __restrict__ rows_token, unsigned short* __restrict__ xg)
{
  const int row = blockIdx.x, t = threadIdx.x;
  const int tok = rows_token[row];
  float4 v = reinterpret_cast<const float4*>(x + (size_t)tok * DIM)[t];
  ushort4 h;
  h.x = f2bf(v.x); h.y = f2bf(v.y); h.z = f2bf(v.z); h.w = f2bf(v.w);
  reinterpret_cast<ushort4*>(xg + (size_t)row * DIM)[t] = h;
}

// ---------------- grouped expert GEMM (fc1 / fc2) ----------------
// BM=128, BN=64, BK=32; 128 threads = 2 waves, each wave a full 64x64 tile
// (acc[4][4], 16 MFMA/k-step).  Depth-2 named-register prefetch.
// Tile assignment from per-XCD lists: xcd = blockIdx&7, slot = blockIdx>>3.
template<bool FC1>
__global__ __launch_bounds__(128) void expert_gemm_k(
    const unsigned short* __restrict__ Ag,
    const float* __restrict__ Wg, const float* __restrict__ bg,
    const int* __restrict__ cnt, const int* __restrict__ basev,
    const int* __restrict__ list, const float* __restrict__ rows_w,
    unsigned short* __restrict__ hout, float* __restrict__ obuf)
{
  constexpr int KD = FC1 ? DIM : HID;
  constexpr int ND = FC1 ? HID : DIM;
  constexpr int BM = 128, BN = 64, BK = 32, LDP = 36;
  constexpr int JC = FC1 ? J1 : J2;
  constexpr int NK = KD / BK;
  const int code = list[(blockIdx.x & 7) * JC + (blockIdx.x >> 3)];
  if (code < 0) return;
  const int e  = code >> 16, m0 = ((code >> 8) & 255) * BM, nt = code & 255;
  const int Ne = cnt[e], base = basev[e];
  __shared__ unsigned short As[BM][LDP];   // 9216 B
  __shared__ unsigned short Bs[BN][LDP];   // 4608 B
  const int tid = threadIdx.x;
  const float* W = Wg + (size_t)e * KD * ND + nt * BN;

  // A staging: 128 rows x 4 kq (8 bf16) = 512 slots / 128 thr = 4 each
  const unsigned short* aptr[4];
  int arow[4], akq[4];
#pragma unroll
  for (int i = 0; i < 4; i++) {
    int flat = tid + 128 * i;
    int row = flat >> 2, kq = flat & 3;
    arow[i] = row; akq[i] = kq;
    int g = m0 + row; if (g >= Ne) g = Ne - 1;
    aptr[i] = Ag + (size_t)(base + g) * KD + kq * 8;
  }
  // B staging: 64 n x 8 kq (4 fp32 rows each) = 512 slots / 128 thr = 4 each
  int bn_[4], bkq[4];
  const float* bptr[4];
#pragma unroll
  for (int i = 0; i < 4; i++) {
    int flat = tid + 128 * i;
    bn_[i] = flat & 63; bkq[i] = flat >> 6;
    bptr[i] = W + (size_t)(bkq[i] * 4) * ND + bn_[i];
  }

  const int wid = tid >> 6, lane = tid & 63;
  const int lr = lane & 15, lg = lane >> 4;
  const bool wactive = (m0 + wid * 64) < Ne;   // 2 waves stacked in m

  f32x4 acc[4][4];
#pragma unroll
  for (int m = 0; m < 4; m++)
#pragma unroll
    for (int n = 0; n < 4; n++) acc[m][n] = (f32x4){0.f, 0.f, 0.f, 0.f};

#define LOAD_SET(A0,A1,A2,A3,B0,B1,B2,B3,K0)                                 \
  A0 = *reinterpret_cast<const short8*>(aptr[0] + (K0));                     \
  A1 = *reinterpret_cast<const short8*>(aptr[1] + (K0));                     \
  A2 = *reinterpret_cast<const short8*>(aptr[2] + (K0));                     \
  A3 = *reinterpret_cast<const short8*>(aptr[3] + (K0));                     \
  { const float* p0 = bptr[0] + (size_t)(K0) * ND;                           \
    B0.x = p0[0]; B0.y = p0[(size_t)ND]; B0.z = p0[2*(size_t)ND]; B0.w = p0[3*(size_t)ND]; \
    const float* p1 = bptr[1] + (size_t)(K0) * ND;                           \
    B1.x = p1[0]; B1.y = p1[(size_t)ND]; B1.z = p1[2*(size_t)ND]; B1.w = p1[3*(size_t)ND]; \
    const float* p2 = bptr[2] + (size_t)(K0) * ND;                           \
    B2.x = p2[0]; B2.y = p2[(size_t)ND]; B2.z = p2[2*(size_t)ND]; B2.w = p2[3*(size_t)ND]; \
    const float* p3 = bptr[3] + (size_t)(K0) * ND;                           \
    B3.x = p3[0]; B3.y = p3[(size_t)ND]; B3.z = p3[2*(size_t)ND]; B3.w = p3[3*(size_t)ND]; }

#define GEMM_STEP(A0,A1,A2,A3,B0,B1,B2,B3,KS)                                \
  __syncthreads();                                                           \
  *reinterpret_cast<short8*>(&As[arow[0]][akq[0] * 8]) = A0;                 \
  *reinterpret_cast<short8*>(&As[arow[1]][akq[1] * 8]) = A1;                 \
  *reinterpret_cast<short8*>(&As[arow[2]][akq[2] * 8]) = A2;                 \
  *reinterpret_cast<short8*>(&As[arow[3]][akq[3] * 8]) = A3;                 \
  { ushort4 h;                                                               \
    h.x = f2bf(B0.x); h.y = f2bf(B0.y); h.z = f2bf(B0.z); h.w = f2bf(B0.w);  \
    *reinterpret_cast<ushort4*>(&Bs[bn_[0]][bkq[0] * 4]) = h;                \
    h.x = f2bf(B1.x); h.y = f2bf(B1.y); h.z = f2bf(B1.z); h.w = f2bf(B1.w);  \
    *reinterpret_cast<ushort4*>(&Bs[bn_[1]][bkq[1] * 4]) = h;                \
    h.x = f2bf(B2.x); h.y = f2bf(B2.y); h.z = f2bf(B2.z); h.w = f2bf(B2.w);  \
    *reinterpret_cast<ushort4*>(&Bs[bn_[2]][bkq[2] * 4]) = h;                \
    h.x = f2bf(B3.x); h.y = f2bf(B3.y); h.z = f2bf(B3.z); h.w = f2bf(B3.w);  \
    *reinterpret_cast<ushort4*>(&Bs[bn_[3]][bkq[3] * 4]) = h; }              \
  __syncthreads();                                                           \
  if ((KS) + 2 < NK) { LOAD_SET(A0,A1,A2,A3,B0,B1,B2,B3, ((KS) + 2) * BK) }  \
  if (wactive) {                                                             \
    short8 af[4], bb[4];                                                     \
    _Pragma("unroll")                                                        \
    for (int m = 0; m < 4; m++)                                              \
      af[m] = *reinterpret_cast<const short8*>(&As[wid*64 + m*16 + lr][lg*8]);\
    _Pragma("unroll")                                                        \
    for (int n = 0; n < 4; n++)                                              \
      bb[n] = *reinterpret_cast<const short8*>(&Bs[n*16 + lr][lg*8]);        \
    _Pragma("unroll")                                                        \
    for (int m = 0; m < 4; m++)                                              \
      _Pragma("unroll")                                                      \
      for (int n = 0; n < 4; n++)                                            \
        acc[m][n] = __builtin_amdgcn_mfma_f32_16x16x32_bf16(af[m], bb[n],    \
                                                            acc[m][n], 0,0,0);\
  }

  // prologue: prefetch k-steps 0 and 1 into the two named register sets
  short8 a0A, a1A, a2A, a3A, a0B, a1B, a2B, a3B;
  float4 b0A, b1A, b2A, b3A, b0B, b1B, b2B, b3B;
  LOAD_SET(a0A, a1A, a2A, a3A, b0A, b1A, b2A, b3A, 0)
  LOAD_SET(a0B, a1B, a2B, a3B, b0B, b1B, b2B, b3B, BK)

  for (int ks = 0; ks < NK; ks += 2) {
    GEMM_STEP(a0A, a1A, a2A, a3A, b0A, b1A, b2A, b3A, ks)
    GEMM_STEP(a0B, a1B, a2B, a3B, b0B, b1B, b2B, b3B, ks + 1)
  }
#undef LOAD_SET
#undef GEMM_STEP

  if (!wactive) return;
  // epilogue: C/D layout col = lane&15, row = (lane>>4)*4 + reg (m89-verified)
#pragma unroll
  for (int n = 0; n < 4; n++) {
    const int col = nt * BN + n * 16 + lr;
    const float bias = bg[(size_t)e * ND + col];
#pragma unroll
    for (int m = 0; m < 4; m++) {
      const int rbase = m0 + wid * 64 + m * 16 + lg * 4;
#pragma unroll
      for (int v = 0; v < 4; v++) {
        const int r = rbase + v;
        if (r < Ne) {
          float val = acc[m][n][v] + bias;
          if constexpr (FC1) {
            val = 0.5f * val * (1.0f + erff(val * 0.70710678118654752440f));  // exact GELU
            hout[(size_t)(base + r) * HID + col] = f2bf(val);
          } else {
            obuf[(size_t)(base + r) * DIM + col] = val * rows_w[base + r];
          }
        }
      }
    }
  }
}

// ---------------- combine: y = x + o[slot0] + o[slot1] ----------------
__global__ __launch_bounds__(256) void combine_k(const float* __restrict__ x,
    const float* __restrict__ obuf, const int* __restrict__ slot_of,
    float* __restrict__ out)
{
  const int t = blockIdx.x, c = threadIdx.x;
  const int s0 = slot_of[2*t], s1 = slot_of[2*t+1];
  const float4 a = reinterpret_cast<const float4*>(x + (size_t)t * DIM)[c];
  const float4 b = reinterpret_cast<const float4*>(obuf + (size_t)s0 * DIM)[c];
  const float4 d = reinterpret_cast<const float4*>(obuf + (size_t)s1 * DIM)[c];
  float4 r;
  r.x = a.x + b.x + d.x; r.y = a.y + b.y + d.y;
  r.z = a.z + b.z + d.z; r.w = a.w + b.w + d.w;
  reinterpret_cast<float4*>(out + (size_t)t * DIM)[c] = r;
}

extern "C" void kernel_launch(void* const* d_in, const int* in_sizes, int n_in,
                              void* d_out, int out_size, void* d_ws, size_t ws_size,
                              hipStream_t stream) {
  const float* x  = (const float*)d_in[0];
  const float* Wr = (const float*)d_in[1];
  const float* br = (const float*)d_in[2];
  const float* W1 = (const float*)d_in[3];
  const float* b1 = (const float*)d_in[4];
  const float* W2 = (const float*)d_in[5];
  const float* b2 = (const float*)d_in[6];
  float* out = (float*)d_out;
  char* ws = (char*)d_ws;

  int*   cnt        = (int*)  (ws + 0);
  int*   fill       = (int*)  (ws + 64);
  int*   basev      = (int*)  (ws + 128);
  int*   list1      = (int*)  (ws + 4096);    // 8*256 ints = 8 KB
  int*   list2      = (int*)  (ws + 12288);   // 8*128 ints = 4 KB
  int*   re         = (int*)  (ws + 16384);
  float* rwv        = (float*)(ws + 32768);
  int*   rows_token = (int*)  (ws + 49152);
  float* rows_w     = (float*)(ws + 65536);
  int*   slot_of    = (int*)  (ws + 81920);
  unsigned short* xg   = (unsigned short*)(ws + ((size_t)(1 << 17)));                      // 4096x1024 bf16 = 8 MB
  unsigned short* hbuf = (unsigned short*)(ws + ((size_t)(1 << 17) + ((size_t)8 << 20)));  // 4096x2048 bf16 = 16 MB
  float* obuf          = (float*)         (ws + ((size_t)(1 << 17) + ((size_t)24 << 20))); // 4096x1024 f32  = 16 MB

  init_k<<<dim3(8), dim3(256), 0, stream>>>(cnt, fill, list1, list2);
  router_k<<<dim3(T_TOK / 4), dim3(256), 0, stream>>>(x, Wr, br, re, rwv, cnt);
  scan_k<<<dim3(1), dim3(64), 0, stream>>>(cnt, basev, list1, list2);
  scatter_k<<<dim3(T_TOK / 256), dim3(256), 0, stream>>>(re, rwv, basev, fill,
                                                         rows_token, rows_w, slot_of);
  gather_k<<<dim3(2 * T_TOK), dim3(256), 0, stream>>>(x, rows_token, xg);
  expert_gemm_k<true><<<dim3(8 * J1), dim3(128), 0, stream>>>(
      xg, W1, b1, cnt, basev, list1, rows_w, hbuf, obuf);
  expert_gemm_k<false><<<dim3(8 * J2), dim3(128), 0, stream>>>(
      hbuf, W2, b2, cnt, basev, list2, rows_w, hbuf, obuf);
  combine_k<<<dim3(T_TOK), dim3(256), 0, stream>>>(x, obuf, slot_of, out);
}

// Round 7
// 286.794 us; speedup vs baseline: 1.6591x; 1.6591x over previous
//
#include <hip/hip_runtime.h>
#include <hip/hip_bf16.h>

#define T_TOK 2048
#define DIM   1024
#define NEXP  16
#define HID   2048
#define MAXMT 48

typedef __attribute__((ext_vector_type(8))) short short8;
typedef __attribute__((ext_vector_type(4))) float f32x4;

__device__ __forceinline__ unsigned short f2bf(float f) {
  __hip_bfloat16 h = __float2bfloat16(f);
  union { __hip_bfloat16 b; unsigned short u; } cv; cv.b = h; return cv.u;
}

// ---------------- init: zero counters ----------------
__global__ void init_k(int* cnt, int* fill) {
  int i = threadIdx.x;
  if (i < NEXP) { cnt[i] = 0; fill[i] = 0; }
}

// ---------------- router: fp32, one wave per token ----------------
__global__ __launch_bounds__(256) void router_k(const float* __restrict__ x,
    const float* __restrict__ Wr, const float* __restrict__ br,
    int* __restrict__ re, float* __restrict__ rwv, int* __restrict__ cnt)
{
  const int wid = threadIdx.x >> 6, lane = threadIdx.x & 63;
  const int t = blockIdx.x * 4 + wid;
  const float* xr = x + (size_t)t * DIM;
  float acc[NEXP];
#pragma unroll
  for (int e = 0; e < NEXP; e++) acc[e] = 0.f;
  for (int i = 0; i < DIM / 64; i++) {
    const int d = lane + 64 * i;
    const float xv = xr[d];
    const float4* w4 = reinterpret_cast<const float4*>(Wr + (size_t)d * NEXP);
#pragma unroll
    for (int q = 0; q < 4; q++) {
      float4 w = w4[q];
      acc[4*q+0] += xv * w.x; acc[4*q+1] += xv * w.y;
      acc[4*q+2] += xv * w.z; acc[4*q+3] += xv * w.w;
    }
  }
#pragma unroll
  for (int e = 0; e < NEXP; e++) {
    float v = acc[e];
    v += __shfl_xor(v, 32); v += __shfl_xor(v, 16); v += __shfl_xor(v, 8);
    v += __shfl_xor(v, 4);  v += __shfl_xor(v, 2);  v += __shfl_xor(v, 1);
    acc[e] = v;
  }
  if (lane == 0) {
    float lg[NEXP];
#pragma unroll
    for (int e = 0; e < NEXP; e++) lg[e] = acc[e] + br[e];  // TEMP = 1.0
    int e0 = 0; float b0 = lg[0];
    for (int e = 1; e < NEXP; e++) if (lg[e] > b0) { b0 = lg[e]; e0 = e; }
    int e1 = (e0 == 0) ? 1 : 0; float b1v = lg[e1];
    for (int e = 0; e < NEXP; e++) if (e != e0 && lg[e] > b1v) { b1v = lg[e]; e1 = e; }
    float p1 = expf(b1v - b0);               // p0 = 1
    float inv = 1.0f / (1.0f + p1);
    re[2*t] = e0; re[2*t+1] = e1;
    rwv[2*t] = inv; rwv[2*t+1] = p1 * inv;
    atomicAdd(&cnt[e0], 1); atomicAdd(&cnt[e1], 1);
  }
}

// ---------------- scan: prefix + flat m-tile list (BM=128), cheap ----------------
__global__ void scan_k(const int* cnt, int* basev, int* tile_e, int* tile_m0, int* ntt) {
  if (threadIdx.x == 0) {
    int s = 0, t = 0;
    for (int e = 0; e < NEXP; e++) {
      basev[e] = s;
      for (int m0 = 0; m0 < cnt[e]; m0 += 128) { tile_e[t] = e; tile_m0[t] = m0; t++; }
      s += cnt[e];
    }
    ntt[0] = t;
  }
}

// ---------------- scatter: build per-expert row lists ----------------
__global__ __launch_bounds__(256) void scatter_k(const int* __restrict__ re,
    const float* __restrict__ rwv, const int* __restrict__ basev, int* fill,
    int* __restrict__ rows_token, float* __restrict__ rows_w, int* __restrict__ slot_of)
{
  int t = blockIdx.x * 256 + threadIdx.x;
  if (t >= T_TOK) return;
  for (int k = 0; k < 2; k++) {
    int e = re[2*t+k];
    int pos = atomicAdd(&fill[e], 1);
    int row = basev[e] + pos;
    rows_token[row] = t;
    rows_w[row] = rwv[2*t+k];
    slot_of[2*t+k] = row;
  }
}

// ---------------- gather: xg[row] = bf16(x[token]) ----------------
__global__ __launch_bounds__(256) void gather_k(const float* __restrict__ x,
    const int* __restrict__ rows_token, unsigned short* __restrict__ xg)
{
  const int row = blockIdx.x, t = threadIdx.x;
  const int tok = rows_token[row];
  float4 v = reinterpret_cast<const float4*>(x + (size_t)tok * DIM)[t];
  ushort4 h;
  h.x = f2bf(v.x); h.y = f2bf(v.y); h.z = f2bf(v.z); h.w = f2bf(v.w);
  reinterpret_cast<ushort4*>(xg + (size_t)row * DIM)[t] = h;
}

// ---------------- grouped expert GEMM (fc1 / fc2, 256 thr = 4 waves) --------
// BM=128, BN=128, BK=32; waves 2x2, each owns 64x64 (acc[4][4], 16 MFMA/step).
// Depth-2 named-register prefetch.  fc2: split-K (KSPLIT via gridDim.z),
// partial written to obuf + kz*T_ROWS*DIM, summed in combine.
template<bool FC1>
__global__ __launch_bounds__(256) void expert_gemm_k(
    const unsigned short* __restrict__ Ag,
    const float* __restrict__ Wg, const float* __restrict__ bg,
    const int* __restrict__ cnt, const int* __restrict__ basev,
    const int* __restrict__ tile_e, const int* __restrict__ tile_m0,
    const int* __restrict__ ntt, const float* __restrict__ rows_w,
    unsigned short* __restrict__ hout, float* __restrict__ obuf)
{
  constexpr int KD = FC1 ? DIM : HID;     // full K of the layer
  constexpr int ND = FC1 ? HID : DIM;
  constexpr int KSPL = FC1 ? 1 : 2;       // split-K factor
  constexpr int KLOC = KD / KSPL;         // K per block
  constexpr int BM = 128, BN = 128, BK = 32, LDP = 36;
  constexpr int NK = KLOC / BK;
  if ((int)blockIdx.y >= ntt[0]) return;
  const int e  = tile_e[blockIdx.y], m0 = tile_m0[blockIdx.y];
  const int Ne = cnt[e], base = basev[e];
  const int nt = blockIdx.x;
  const int kz = blockIdx.z;
  const int kbase = kz * KLOC;
  __shared__ unsigned short As[BM][LDP];   // 9216 B
  __shared__ unsigned short Bs[BN][LDP];   // 9216 B
  const int tid = threadIdx.x;
  const float* W = Wg + (size_t)e * KD * ND + (size_t)kbase * ND + nt * BN;

  // A staging: 128 rows x 4 kq (8 bf16) = 512 slots / 256 thr = 2 each
  const unsigned short* aptr[2];
  int arow[2], akq[2];
#pragma unroll
  for (int i = 0; i < 2; i++) {
    int flat = tid + 256 * i;
    int row = flat >> 2, kq = flat & 3;
    arow[i] = row; akq[i] = kq;
    int g = m0 + row; if (g >= Ne) g = Ne - 1;
    aptr[i] = Ag + (size_t)(base + g) * KD + kbase + kq * 8;
  }
  // B staging: 128 n x 8 kq (4 fp32 rows each) = 1024 slots / 256 thr = 4 each
  int bn_[4], bkq[4];
  const float* bptr[4];
#pragma unroll
  for (int i = 0; i < 4; i++) {
    int flat = tid + 256 * i;
    bn_[i] = flat & 127; bkq[i] = flat >> 7;
    bptr[i] = W + (size_t)(bkq[i] * 4) * ND + bn_[i];
  }

  const int wid = tid >> 6, lane = tid & 63;
  const int wr = wid >> 1, wc = wid & 1;     // 2 m-bands x 2 n-bands of 64
  const int lr = lane & 15, lg = lane >> 4;
  const bool wactive = (m0 + wr * 64) < Ne;

  f32x4 acc[4][4];
#pragma unroll
  for (int m = 0; m < 4; m++)
#pragma unroll
    for (int n = 0; n < 4; n++) acc[m][n] = (f32x4){0.f, 0.f, 0.f, 0.f};

#define LOAD_SET(A0,A1,B0,B1,B2,B3,K0)                                       \
  A0 = *reinterpret_cast<const short8*>(aptr[0] + (K0));                     \
  A1 = *reinterpret_cast<const short8*>(aptr[1] + (K0));                     \
  { const float* p0 = bptr[0] + (size_t)(K0) * ND;                           \
    B0.x = p0[0]; B0.y = p0[(size_t)ND]; B0.z = p0[2*(size_t)ND]; B0.w = p0[3*(size_t)ND]; \
    const float* p1 = bptr[1] + (size_t)(K0) * ND;                           \
    B1.x = p1[0]; B1.y = p1[(size_t)ND]; B1.z = p1[2*(size_t)ND]; B1.w = p1[3*(size_t)ND]; \
    const float* p2 = bptr[2] + (size_t)(K0) * ND;                           \
    B2.x = p2[0]; B2.y = p2[(size_t)ND]; B2.z = p2[2*(size_t)ND]; B2.w = p2[3*(size_t)ND]; \
    const float* p3 = bptr[3] + (size_t)(K0) * ND;                           \
    B3.x = p3[0]; B3.y = p3[(size_t)ND]; B3.z = p3[2*(size_t)ND]; B3.w = p3[3*(size_t)ND]; }

#define GEMM_STEP(A0,A1,B0,B1,B2,B3,KS)                                      \
  __syncthreads();                                                           \
  *reinterpret_cast<short8*>(&As[arow[0]][akq[0] * 8]) = A0;                 \
  *reinterpret_cast<short8*>(&As[arow[1]][akq[1] * 8]) = A1;                 \
  { ushort4 h;                                                               \
    h.x = f2bf(B0.x); h.y = f2bf(B0.y); h.z = f2bf(B0.z); h.w = f2bf(B0.w);  \
    *reinterpret_cast<ushort4*>(&Bs[bn_[0]][bkq[0] * 4]) = h;                \
    h.x = f2bf(B1.x); h.y = f2bf(B1.y); h.z = f2bf(B1.z); h.w = f2bf(B1.w);  \
    *reinterpret_cast<ushort4*>(&Bs[bn_[1]][bkq[1] * 4]) = h;                \
    h.x = f2bf(B2.x); h.y = f2bf(B2.y); h.z = f2bf(B2.z); h.w = f2bf(B2.w);  \
    *reinterpret_cast<ushort4*>(&Bs[bn_[2]][bkq[2] * 4]) = h;                \
    h.x = f2bf(B3.x); h.y = f2bf(B3.y); h.z = f2bf(B3.z); h.w = f2bf(B3.w);  \
    *reinterpret_cast<ushort4*>(&Bs[bn_[3]][bkq[3] * 4]) = h; }              \
  __syncthreads();                                                           \
  if ((KS) + 2 < NK) { LOAD_SET(A0,A1,B0,B1,B2,B3, ((KS) + 2) * BK) }        \
  if (wactive) {                                                             \
    short8 af[4], bb[4];                                                     \
    _Pragma("unroll")                                                        \
    for (int m = 0; m < 4; m++)                                              \
      af[m] = *reinterpret_cast<const short8*>(&As[wr*64 + m*16 + lr][lg*8]);\
    _Pragma("unroll")                                                        \
    for (int n = 0; n < 4; n++)                                              \
      bb[n] = *reinterpret_cast<const short8*>(&Bs[wc*64 + n*16 + lr][lg*8]);\
    _Pragma("unroll")                                                        \
    for (int m = 0; m < 4; m++)                                              \
      _Pragma("unroll")                                                      \
      for (int n = 0; n < 4; n++)                                            \
        acc[m][n] = __builtin_amdgcn_mfma_f32_16x16x32_bf16(af[m], bb[n],    \
                                                            acc[m][n], 0,0,0);\
  }

  // prologue: prefetch k-steps 0 and 1 into the two named register sets
  short8 a0A, a1A, a0B, a1B;
  float4 b0A, b1A, b2A, b3A, b0B, b1B, b2B, b3B;
  LOAD_SET(a0A, a1A, b0A, b1A, b2A, b3A, 0)
  LOAD_SET(a0B, a1B, b0B, b1B, b2B, b3B, BK)

  for (int ks = 0; ks < NK; ks += 2) {
    GEMM_STEP(a0A, a1A, b0A, b1A, b2A, b3A, ks)
    GEMM_STEP(a0B, a1B, b0B, b1B, b2B, b3B, ks + 1)
  }
#undef LOAD_SET
#undef GEMM_STEP

  if (!wactive) return;
  // epilogue: C/D layout col = lane&15, row = (lane>>4)*4 + reg (m89-verified)
#pragma unroll
  for (int n = 0; n < 4; n++) {
    const int col = nt * BN + wc * 64 + n * 16 + lr;
    const float bias = (kz == 0) ? bg[(size_t)e * ND + col] : 0.f;
#pragma unroll
    for (int m = 0; m < 4; m++) {
      const int rbase = m0 + wr * 64 + m * 16 + lg * 4;
#pragma unroll
      for (int v = 0; v < 4; v++) {
        const int r = rbase + v;
        if (r < Ne) {
          float val = acc[m][n][v] + bias;
          if constexpr (FC1) {
            val = 0.5f * val * (1.0f + erff(val * 0.70710678118654752440f));  // exact GELU
            hout[(size_t)(base + r) * HID + col] = f2bf(val);
          } else {
            obuf[(size_t)kz * (2 * T_TOK) * DIM + (size_t)(base + r) * DIM + col]
                = val * rows_w[base + r];
          }
        }
      }
    }
  }
}

// ---------------- combine: y = x + sum of 2 split-K partials per slot ------
__global__ __launch_bounds__(256) void combine_k(const float* __restrict__ x,
    const float* __restrict__ obuf, const int* __restrict__ slot_of,
    float* __restrict__ out)
{
  const int t = blockIdx.x, c = threadIdx.x;
  const int s0 = slot_of[2*t], s1 = slot_of[2*t+1];
  const size_t PSZ = (size_t)(2 * T_TOK) * DIM;
  const float4 a  = reinterpret_cast<const float4*>(x + (size_t)t * DIM)[c];
  const float4 p0 = reinterpret_cast<const float4*>(obuf + (size_t)s0 * DIM)[c];
  const float4 p1 = reinterpret_cast<const float4*>(obuf + PSZ + (size_t)s0 * DIM)[c];
  const float4 q0 = reinterpret_cast<const float4*>(obuf + (size_t)s1 * DIM)[c];
  const float4 q1 = reinterpret_cast<const float4*>(obuf + PSZ + (size_t)s1 * DIM)[c];
  float4 r;
  r.x = a.x + p0.x + p1.x + q0.x + q1.x;
  r.y = a.y + p0.y + p1.y + q0.y + q1.y;
  r.z = a.z + p0.z + p1.z + q0.z + q1.z;
  r.w = a.w + p0.w + p1.w + q0.w + q1.w;
  reinterpret_cast<float4*>(out + (size_t)t * DIM)[c] = r;
}

extern "C" void kernel_launch(void* const* d_in, const int* in_sizes, int n_in,
                              void* d_out, int out_size, void* d_ws, size_t ws_size,
                              hipStream_t stream) {
  const float* x  = (const float*)d_in[0];
  const float* Wr = (const float*)d_in[1];
  const float* br = (const float*)d_in[2];
  const float* W1 = (const float*)d_in[3];
  const float* b1 = (const float*)d_in[4];
  const float* W2 = (const float*)d_in[5];
  const float* b2 = (const float*)d_in[6];
  float* out = (float*)d_out;
  char* ws = (char*)d_ws;

  int*   cnt        = (int*)  (ws + 0);
  int*   fill       = (int*)  (ws + 64);
  int*   basev      = (int*)  (ws + 128);
  int*   ntt        = (int*)  (ws + 192);
  int*   tile_e     = (int*)  (ws + 1024);    // up to 64 tiles
  int*   tile_m0    = (int*)  (ws + 2048);
  int*   re         = (int*)  (ws + 16384);
  float* rwv        = (float*)(ws + 32768);
  int*   rows_token = (int*)  (ws + 49152);
  float* rows_w     = (float*)(ws + 65536);
  int*   slot_of    = (int*)  (ws + 81920);
  unsigned short* xg   = (unsigned short*)(ws + ((size_t)(1 << 17)));                      // 4096x1024 bf16 = 8 MB
  unsigned short* hbuf = (unsigned short*)(ws + ((size_t)(1 << 17) + ((size_t)8 << 20)));  // 4096x2048 bf16 = 16 MB
  float* obuf          = (float*)         (ws + ((size_t)(1 << 17) + ((size_t)24 << 20))); // 2x 4096x1024 f32 = 32 MB

  init_k<<<dim3(1), dim3(64), 0, stream>>>(cnt, fill);
  router_k<<<dim3(T_TOK / 4), dim3(256), 0, stream>>>(x, Wr, br, re, rwv, cnt);
  scan_k<<<dim3(1), dim3(64), 0, stream>>>(cnt, basev, tile_e, tile_m0, ntt);
  scatter_k<<<dim3(T_TOK / 256), dim3(256), 0, stream>>>(re, rwv, basev, fill,
                                                         rows_token, rows_w, slot_of);
  gather_k<<<dim3(2 * T_TOK), dim3(256), 0, stream>>>(x, rows_token, xg);
  expert_gemm_k<true><<<dim3(HID / 128, MAXMT, 1), dim3(256), 0, stream>>>(
      xg, W1, b1, cnt, basev, tile_e, tile_m0, ntt, rows_w, hbuf, obuf);
  expert_gemm_k<false><<<dim3(DIM / 128, MAXMT, 2), dim3(256), 0, stream>>>(
      hbuf, W2, b2, cnt, basev, tile_e, tile_m0, ntt, rows_w, hbuf, obuf);
  combine_k<<<dim3(T_TOK), dim3(256), 0, stream>>>(x, obuf, slot_of, out);
}

// Round 8
// 263.943 us; speedup vs baseline: 1.8027x; 1.0866x over previous
//
#include <hip/hip_runtime.h>
#include <hip/hip_bf16.h>

#define T_TOK 2048
#define DIM   1024
#define NEXP  16
#define HID   2048
#define MAXMT 48

typedef __attribute__((ext_vector_type(8))) short short8;
typedef __attribute__((ext_vector_type(4))) float f32x4;

__device__ __forceinline__ unsigned short f2bf(float f) {
  __hip_bfloat16 h = __float2bfloat16(f);
  union { __hip_bfloat16 b; unsigned short u; } cv; cv.b = h; return cv.u;
}

// ---------------- init: zero counters ----------------
__global__ void init_k(int* cnt, int* fill) {
  int i = threadIdx.x;
  if (i < NEXP) { cnt[i] = 0; fill[i] = 0; }
}

// ---------------- router: fp32, one wave per token ----------------
__global__ __launch_bounds__(256) void router_k(const float* __restrict__ x,
    const float* __restrict__ Wr, const float* __restrict__ br,
    int* __restrict__ re, float* __restrict__ rwv, int* __restrict__ cnt)
{
  const int wid = threadIdx.x >> 6, lane = threadIdx.x & 63;
  const int t = blockIdx.x * 4 + wid;
  const float* xr = x + (size_t)t * DIM;
  float acc[NEXP];
#pragma unroll
  for (int e = 0; e < NEXP; e++) acc[e] = 0.f;
  for (int i = 0; i < DIM / 64; i++) {
    const int d = lane + 64 * i;
    const float xv = xr[d];
    const float4* w4 = reinterpret_cast<const float4*>(Wr + (size_t)d * NEXP);
#pragma unroll
    for (int q = 0; q < 4; q++) {
      float4 w = w4[q];
      acc[4*q+0] += xv * w.x; acc[4*q+1] += xv * w.y;
      acc[4*q+2] += xv * w.z; acc[4*q+3] += xv * w.w;
    }
  }
#pragma unroll
  for (int e = 0; e < NEXP; e++) {
    float v = acc[e];
    v += __shfl_xor(v, 32); v += __shfl_xor(v, 16); v += __shfl_xor(v, 8);
    v += __shfl_xor(v, 4);  v += __shfl_xor(v, 2);  v += __shfl_xor(v, 1);
    acc[e] = v;
  }
  if (lane == 0) {
    float lg[NEXP];
#pragma unroll
    for (int e = 0; e < NEXP; e++) lg[e] = acc[e] + br[e];  // TEMP = 1.0
    int e0 = 0; float b0 = lg[0];
    for (int e = 1; e < NEXP; e++) if (lg[e] > b0) { b0 = lg[e]; e0 = e; }
    int e1 = (e0 == 0) ? 1 : 0; float b1v = lg[e1];
    for (int e = 0; e < NEXP; e++) if (e != e0 && lg[e] > b1v) { b1v = lg[e]; e1 = e; }
    float p1 = expf(b1v - b0);               // p0 = 1
    float inv = 1.0f / (1.0f + p1);
    re[2*t] = e0; re[2*t+1] = e1;
    rwv[2*t] = inv; rwv[2*t+1] = p1 * inv;
    atomicAdd(&cnt[e0], 1); atomicAdd(&cnt[e1], 1);
  }
}

// ---------------- scan: prefix + flat m-tile list (BM=128) ----------------
__global__ void scan_k(const int* cnt, int* basev, int* tile_e, int* tile_m0, int* ntt) {
  if (threadIdx.x == 0) {
    int s = 0, t = 0;
    for (int e = 0; e < NEXP; e++) {
      basev[e] = s;
      for (int m0 = 0; m0 < cnt[e]; m0 += 128) { tile_e[t] = e; tile_m0[t] = m0; t++; }
      s += cnt[e];
    }
    ntt[0] = t;
  }
}

// ---------------- scatter: build per-expert row lists ----------------
__global__ __launch_bounds__(256) void scatter_k(const int* __restrict__ re,
    const float* __restrict__ rwv, const int* __restrict__ basev, int* fill,
    int* __restrict__ rows_token, float* __restrict__ rows_w, int* __restrict__ slot_of)
{
  int t = blockIdx.x * 256 + threadIdx.x;
  if (t >= T_TOK) return;
  for (int k = 0; k < 2; k++) {
    int e = re[2*t+k];
    int pos = atomicAdd(&fill[e], 1);
    int row = basev[e] + pos;
    rows_token[row] = t;
    rows_w[row] = rwv[2*t+k];
    slot_of[2*t+k] = row;
  }
}

// ---------------- gather: xg[row] = bf16(x[token]) ----------------
__global__ __launch_bounds__(256) void gather_k(const float* __restrict__ x,
    const int* __restrict__ rows_token, unsigned short* __restrict__ xg)
{
  const int row = blockIdx.x, t = threadIdx.x;
  const int tok = rows_token[row];
  float4 v = reinterpret_cast<const float4*>(x + (size_t)tok * DIM)[t];
  ushort4 h;
  h.x = f2bf(v.x); h.y = f2bf(v.y); h.z = f2bf(v.z); h.w = f2bf(v.w);
  reinterpret_cast<ushort4*>(xg + (size_t)row * DIM)[t] = h;
}

// ---------------- grouped expert GEMM (fc1 / fc2) ----------------
// BM=128, BN=128, BK=64 phase; 256 thr = 4 waves (2x2), wave tile 64x64,
// acc[4][4], 32 MFMA/wave/phase.  Depth-2 named-set prefetch: loads for
// phase p+2 issued during phase p -> ~2 full phases in flight before the
// barrier drain touches them (issue-to-drain > HBM latency).
// fc2: split-K=2 via gridDim.z, partials summed in combine.
template<bool FC1>
__global__ __launch_bounds__(256, 2) void expert_gemm_k(
    const unsigned short* __restrict__ Ag,
    const float* __restrict__ Wg, const float* __restrict__ bg,
    const int* __restrict__ cnt, const int* __restrict__ basev,
    const int* __restrict__ tile_e, const int* __restrict__ tile_m0,
    const int* __restrict__ ntt, const float* __restrict__ rows_w,
    unsigned short* __restrict__ hout, float* __restrict__ obuf)
{
  constexpr int KD = FC1 ? DIM : HID;     // full K of the layer
  constexpr int ND = FC1 ? HID : DIM;
  constexpr int KSPL = FC1 ? 1 : 2;       // split-K factor
  constexpr int KLOC = KD / KSPL;         // K per block
  constexpr int BM = 128, BN = 128, BK = 64;
  constexpr int NPH = KLOC / BK;          // 16 phases both layers
  if ((int)blockIdx.y >= ntt[0]) return;
  const int e  = tile_e[blockIdx.y], m0 = tile_m0[blockIdx.y];
  const int Ne = cnt[e], base = basev[e];
  const int nt = blockIdx.x;
  const int kz = blockIdx.z;
  const int kbase = kz * KLOC;
  __shared__ unsigned short As[BM][72];   // 18432 B (row 144 B -> 2-way bank alias, free)
  __shared__ unsigned short Bs[BN][72];   // 18432 B
  const int tid = threadIdx.x;
  const float* W = Wg + (size_t)e * KD * ND + (size_t)kbase * ND + nt * BN;

  // A: 128 rows x 8 kq(8 bf16) = 1024 slots / 256 thr = 4 each
  //    row_i = (tid>>3) + 32*i, kq = tid&7
  const unsigned short* aptr[4];
#pragma unroll
  for (int i = 0; i < 4; i++) {
    int g = m0 + (tid >> 3) + 32 * i; if (g >= Ne) g = Ne - 1;
    aptr[i] = Ag + (size_t)(base + g) * KD + kbase + (tid & 7) * 8;
  }
  // B: 128 n x 16 kq(4 k-rows) = 2048 slots / 256 thr = 8 each
  //    n = tid&127, kq_i = (tid>>7) + 2*i  -> single folded base
  const float* bbase = W + (size_t)((tid >> 7) * 4) * ND + (tid & 127);

  const int wid = tid >> 6, lane = tid & 63;
  const int wr = wid >> 1, wc = wid & 1;     // 2 m-bands x 2 n-bands of 64
  const int lr = lane & 15, lg = lane >> 4;
  const bool wactive = (m0 + wr * 64) < Ne;

  f32x4 acc[4][4];
#pragma unroll
  for (int m = 0; m < 4; m++)
#pragma unroll
    for (int n = 0; n < 4; n++) acc[m][n] = (f32x4){0.f, 0.f, 0.f, 0.f};

#define LOAD_SET(VA, VB, K0)                                                 \
  { _Pragma("unroll")                                                        \
    for (int i = 0; i < 4; i++)                                              \
      VA[i] = *reinterpret_cast<const short8*>(aptr[i] + (K0));              \
    _Pragma("unroll")                                                        \
    for (int i = 0; i < 8; i++) {                                            \
      const float* p = bbase + (size_t)((K0) + 8 * i) * ND;                  \
      VB[i].x = p[0]; VB[i].y = p[(size_t)ND];                               \
      VB[i].z = p[2 * (size_t)ND]; VB[i].w = p[3 * (size_t)ND];              \
    } }

#define STORE_SET(VA, VB)                                                    \
  { _Pragma("unroll")                                                        \
    for (int i = 0; i < 4; i++)                                              \
      *reinterpret_cast<short8*>(&As[(tid >> 3) + 32 * i][(tid & 7) * 8]) = VA[i]; \
    _Pragma("unroll")                                                        \
    for (int i = 0; i < 8; i++) {                                            \
      ushort4 h;                                                             \
      h.x = f2bf(VB[i].x); h.y = f2bf(VB[i].y);                              \
      h.z = f2bf(VB[i].z); h.w = f2bf(VB[i].w);                              \
      *reinterpret_cast<ushort4*>(&Bs[tid & 127][((tid >> 7) + 2 * i) * 4]) = h; \
    } }

#define MFMA_HALF(H)                                                         \
  if (wactive) {                                                             \
    short8 af[4], bb[4];                                                     \
    _Pragma("unroll")                                                        \
    for (int m = 0; m < 4; m++)                                              \
      af[m] = *reinterpret_cast<const short8*>(&As[wr*64 + m*16 + lr][(H)*32 + lg*8]); \
    _Pragma("unroll")                                                        \
    for (int n = 0; n < 4; n++)                                              \
      bb[n] = *reinterpret_cast<const short8*>(&Bs[wc*64 + n*16 + lr][(H)*32 + lg*8]); \
    _Pragma("unroll")                                                        \
    for (int m = 0; m < 4; m++)                                              \
      _Pragma("unroll")                                                      \
      for (int n = 0; n < 4; n++)                                            \
        acc[m][n] = __builtin_amdgcn_mfma_f32_16x16x32_bf16(af[m], bb[n],    \
                                                            acc[m][n], 0,0,0);\
  }

#define PHASE(VA, VB, PH)                                                    \
  STORE_SET(VA, VB)                                                          \
  __syncthreads();                                                           \
  if ((PH) + 2 < NPH) { LOAD_SET(VA, VB, ((PH) + 2) * BK) }                  \
  __builtin_amdgcn_s_setprio(1);                                             \
  MFMA_HALF(0)                                                               \
  MFMA_HALF(1)                                                               \
  __builtin_amdgcn_s_setprio(0);                                             \
  __syncthreads();

  // prologue: prefetch phases 0 and 1 into the two named register sets
  short8 vaP[4], vaQ[4];
  float4 vbP[8], vbQ[8];
  LOAD_SET(vaP, vbP, 0)
  LOAD_SET(vaQ, vbQ, BK)

  for (int ph = 0; ph < NPH; ph += 2) {
    PHASE(vaP, vbP, ph)
    PHASE(vaQ, vbQ, ph + 1)
  }
#undef LOAD_SET
#undef STORE_SET
#undef MFMA_HALF
#undef PHASE

  if (!wactive) return;
  // epilogue: C/D layout col = lane&15, row = (lane>>4)*4 + reg (m89-verified)
#pragma unroll
  for (int n = 0; n < 4; n++) {
    const int col = nt * BN + wc * 64 + n * 16 + lr;
    const float bias = (kz == 0) ? bg[(size_t)e * ND + col] : 0.f;
#pragma unroll
    for (int m = 0; m < 4; m++) {
      const int rbase = m0 + wr * 64 + m * 16 + lg * 4;
#pragma unroll
      for (int v = 0; v < 4; v++) {
        const int r = rbase + v;
        if (r < Ne) {
          float val = acc[m][n][v] + bias;
          if constexpr (FC1) {
            val = 0.5f * val * (1.0f + erff(val * 0.70710678118654752440f));  // exact GELU
            hout[(size_t)(base + r) * HID + col] = f2bf(val);
          } else {
            obuf[(size_t)kz * (2 * T_TOK) * DIM + (size_t)(base + r) * DIM + col]
                = val * rows_w[base + r];
          }
        }
      }
    }
  }
}

// ---------------- combine: y = x + sum of 2 split-K partials per slot ------
__global__ __launch_bounds__(256) void combine_k(const float* __restrict__ x,
    const float* __restrict__ obuf, const int* __restrict__ slot_of,
    float* __restrict__ out)
{
  const int t = blockIdx.x, c = threadIdx.x;
  const int s0 = slot_of[2*t], s1 = slot_of[2*t+1];
  const size_t PSZ = (size_t)(2 * T_TOK) * DIM;
  const float4 a  = reinterpret_cast<const float4*>(x + (size_t)t * DIM)[c];
  const float4 p0 = reinterpret_cast<const float4*>(obuf + (size_t)s0 * DIM)[c];
  const float4 p1 = reinterpret_cast<const float4*>(obuf + PSZ + (size_t)s0 * DIM)[c];
  const float4 q0 = reinterpret_cast<const float4*>(obuf + (size_t)s1 * DIM)[c];
  const float4 q1 = reinterpret_cast<const float4*>(obuf + PSZ + (size_t)s1 * DIM)[c];
  float4 r;
  r.x = a.x + p0.x + p1.x + q0.x + q1.x;
  r.y = a.y + p0.y + p1.y + q0.y + q1.y;
  r.z = a.z + p0.z + p1.z + q0.z + q1.z;
  r.w = a.w + p0.w + p1.w + q0.w + q1.w;
  reinterpret_cast<float4*>(out + (size_t)t * DIM)[c] = r;
}

extern "C" void kernel_launch(void* const* d_in, const int* in_sizes, int n_in,
                              void* d_out, int out_size, void* d_ws, size_t ws_size,
                              hipStream_t stream) {
  const float* x  = (const float*)d_in[0];
  const float* Wr = (const float*)d_in[1];
  const float* br = (const float*)d_in[2];
  const float* W1 = (const float*)d_in[3];
  const float* b1 = (const float*)d_in[4];
  const float* W2 = (const float*)d_in[5];
  const float* b2 = (const float*)d_in[6];
  float* out = (float*)d_out;
  char* ws = (char*)d_ws;

  int*   cnt        = (int*)  (ws + 0);
  int*   fill       = (int*)  (ws + 64);
  int*   basev      = (int*)  (ws + 128);
  int*   ntt        = (int*)  (ws + 192);
  int*   tile_e     = (int*)  (ws + 1024);    // up to 64 tiles
  int*   tile_m0    = (int*)  (ws + 2048);
  int*   re         = (int*)  (ws + 16384);
  float* rwv        = (float*)(ws + 32768);
  int*   rows_token = (int*)  (ws + 49152);
  float* rows_w     = (float*)(ws + 65536);
  int*   slot_of    = (int*)  (ws + 81920);
  unsigned short* xg   = (unsigned short*)(ws + ((size_t)(1 << 17)));                      // 4096x1024 bf16 = 8 MB
  unsigned short* hbuf = (unsigned short*)(ws + ((size_t)(1 << 17) + ((size_t)8 << 20)));  // 4096x2048 bf16 = 16 MB
  float* obuf          = (float*)         (ws + ((size_t)(1 << 17) + ((size_t)24 << 20))); // 2x 4096x1024 f32 = 32 MB

  init_k<<<dim3(1), dim3(64), 0, stream>>>(cnt, fill);
  router_k<<<dim3(T_TOK / 4), dim3(256), 0, stream>>>(x, Wr, br, re, rwv, cnt);
  scan_k<<<dim3(1), dim3(64), 0, stream>>>(cnt, basev, tile_e, tile_m0, ntt);
  scatter_k<<<dim3(T_TOK / 256), dim3(256), 0, stream>>>(re, rwv, basev, fill,
                                                         rows_token, rows_w, slot_of);
  gather_k<<<dim3(2 * T_TOK), dim3(256), 0, stream>>>(x, rows_token, xg);
  expert_gemm_k<true><<<dim3(HID / 128, MAXMT, 1), dim3(256), 0, stream>>>(
      xg, W1, b1, cnt, basev, tile_e, tile_m0, ntt, rows_w, hbuf, obuf);
  expert_gemm_k<false><<<dim3(DIM / 128, MAXMT, 2), dim3(256), 0, stream>>>(
      hbuf, W2, b2, cnt, basev, tile_e, tile_m0, ntt, rows_w, hbuf, obuf);
  combine_k<<<dim3(T_TOK), dim3(256), 0, stream>>>(x, obuf, slot_of, out);
}